// Round 16
// baseline (1137.836 us; speedup 1.0000x reference)
//
#include <hip/hip_runtime.h>
#include <hip/hip_bf16.h>

// Problem constants (match reference)
#define B_GR   128
#define GWID   30
#define IWID   90
#define C_IN   32
#define R_REL  8
#define NBAS   4
#define N_NODES (B_GR*GWID*GWID)   // 115200
#define E_EDGES (N_NODES*8)        // 921600
#define NEG_SLOPE 0.01f

#define SCAN_BLOCKS (N_NODES/256)  // 450
#define DBUCK 64

typedef __attribute__((ext_vector_type(8))) __bf16 bf16x8;
typedef __attribute__((ext_vector_type(4))) float f32x4;

// ======================================================================
// Weight prep: Bt[b][c][k] = bf16(bases[b][k][c])  (B^T per base)
//              loopt[c][k] = bf16(loopw[k][c])
// ======================================================================
__global__ void k_bases_t(const float* __restrict__ bases, __bf16* __restrict__ Bt,
                          int din, int dout) {
    int idx = blockIdx.x*256 + threadIdx.x;
    int tot = NBAS*din*dout;
    if (idx >= tot) return;
    int b = idx/(dout*din), rem = idx%(dout*din);
    int c = rem/din, k = rem%din;
    Bt[idx] = (__bf16)bases[((size_t)b*din + k)*dout + c];
}
__global__ void k_loop_t(const float* __restrict__ loopw, __bf16* __restrict__ loopt,
                         int din, int dout) {
    int idx = blockIdx.x*256 + threadIdx.x;
    if (idx >= din*dout) return;
    int c = idx/din, k = idx%din;
    loopt[idx] = (__bf16)loopw[(size_t)k*dout + c];
}

// ======================================================================
// prep: plain dst-CSR, single scatter with fused 8B metadata per edge:
//   pmeta[j] = { src | et<<24 , bits(norm) }
// ======================================================================
__global__ void k_deg(const int* __restrict__ dst, int* __restrict__ deg) {
    int e = blockIdx.x*256 + threadIdx.x;
    if (e < E_EDGES) atomicAdd(&deg[dst[e]], 1);
}
__global__ __launch_bounds__(256) void k_scan1(const int* __restrict__ deg,
                                               int* __restrict__ rowptr,
                                               int* __restrict__ bsum) {
    __shared__ int s[256], s2[256];
    const int tid = threadIdx.x, gid = blockIdx.x*256 + tid;
    int v = deg[gid];
    s[tid] = v;
    __syncthreads();
    int* cur = s; int* nxt = s2;
    for (int d = 1; d < 256; d <<= 1) {
        int val = cur[tid];
        if (tid >= d) val += cur[tid - d];
        nxt[tid] = val;
        __syncthreads();
        int* t = cur; cur = nxt; nxt = t;
    }
    rowptr[gid] = cur[tid] - v;
    if (tid == 255) bsum[blockIdx.x] = cur[255];
}
__global__ __launch_bounds__(512) void k_scan2(int* __restrict__ bsum, int* __restrict__ rowptr) {
    __shared__ int s[512], s2[512];
    const int tid = threadIdx.x;
    int v = (tid < SCAN_BLOCKS) ? bsum[tid] : 0;
    s[tid] = v;
    __syncthreads();
    int* cur = s; int* nxt = s2;
    for (int d = 1; d < 512; d <<= 1) {
        int val = cur[tid];
        if (tid >= d) val += cur[tid - d];
        nxt[tid] = val;
        __syncthreads();
        int* t = cur; cur = nxt; nxt = t;
    }
    if (tid < SCAN_BLOCKS) bsum[tid] = cur[tid] - v;   // exclusive
    if (tid == 0) rowptr[N_NODES] = E_EDGES;
}
__global__ void k_scan3(int* __restrict__ rowptr, const int* __restrict__ bsum,
                        int* __restrict__ cursor) {
    int gid = blockIdx.x*256 + threadIdx.x;
    int v = rowptr[gid] + bsum[blockIdx.x];
    rowptr[gid] = v;
    cursor[gid] = v;
}
__global__ void k_scatter_pack(const int* __restrict__ src, const int* __restrict__ dst,
                               const int* __restrict__ et, const float* __restrict__ norm,
                               int* __restrict__ cursor, int2* __restrict__ pmeta) {
    int e = blockIdx.x*256 + threadIdx.x;
    if (e < E_EDGES) {
        int pos = atomicAdd(&cursor[dst[e]], 1);
        int2 m;
        m.x = src[e] | (et[e] << 24);
        m.y = __float_as_int(norm[e]);
        pmeta[pos] = m;
    }
}

// ======================================================================
// degree-sorted node permutation (counting sort, 64 buckets)
// ======================================================================
__global__ void k_hist_deg(const int* __restrict__ rowptr, int* __restrict__ dhist) {
    int n = blockIdx.x*256 + threadIdx.x;
    if (n >= N_NODES) return;
    int d = rowptr[n+1] - rowptr[n];
    atomicAdd(&dhist[d < DBUCK ? d : DBUCK-1], 1);
}
__global__ void k_scan64(const int* __restrict__ dhist, int* __restrict__ dcur) {
    if (threadIdx.x == 0 && blockIdx.x == 0) {
        int acc = 0;
        for (int i = 0; i < DBUCK; ++i) { dcur[i] = acc; acc += dhist[i]; }
    }
}
__global__ void k_scatter_perm(const int* __restrict__ rowptr, int* __restrict__ dcur,
                               int* __restrict__ perm) {
    int n = blockIdx.x*256 + threadIdx.x;
    if (n >= N_NODES) return;
    int d = rowptr[n+1] - rowptr[n];
    int pos = atomicAdd(&dcur[d < DBUCK ? d : DBUCK-1], 1);
    perm[pos] = n;
}

// ======================================================================
// Fused basis RGCN layer (R13 structure + degree-sorted node order):
//   hout[n] = act( sum_b (sum_e norm*comp[et,b]*h[src]) @ B_b + h[n]@loopw + bias )
// Wave owns 16 PERM-CONSECUTIVE nodes (near-equal degree -> wave-max trip
// ~= mean ~= 8 instead of ~16). Single-pass gather, meta prefetch 1 ahead.
// Lane l: m=l&15 (row), g=l>>4 (K-subgroup). D: row g*4+ri, col nf*16+m.
// ======================================================================
template<int DIN, int DOUT, int ACT, int IN_F32, int OUT_F32, int MINW>
__global__ __launch_bounds__(256, MINW) void k_fusedb(
        const void* __restrict__ hin, const __bf16* __restrict__ Bt,
        const __bf16* __restrict__ loopt, const float* __restrict__ bias,
        const float* __restrict__ comp, const int* __restrict__ rowptr,
        const int2* __restrict__ pmeta, const int* __restrict__ perm,
        void* __restrict__ hout) {
    constexpr int KS = DIN/32;
    constexpr int NF = DOUT/16;
    const int tid = threadIdx.x;
    const int w = tid >> 6, l = tid & 63;
    const int m = l & 15, g = l >> 4;
    const int nb = blockIdx.x*64 + w*16;
    const int node = perm[nb + m];

    f32x4 acc[NF];
    #pragma unroll
    for (int nf = 0; nf < NF; ++nf) acc[nf] = (f32x4){0.f,0.f,0.f,0.f};

    // ---- single-pass gather into 4 basis accumulators ----
    float ka[NBAS][KS][8];
    #pragma unroll
    for (int b = 0; b < NBAS; ++b)
        #pragma unroll
        for (int ks = 0; ks < KS; ++ks)
            #pragma unroll
            for (int c = 0; c < 8; ++c) ka[b][ks][c] = 0.f;

    const int jb = rowptr[node], je = rowptr[node+1];
    int2 mt = pmeta[jb];                 // safe: pmeta padded
    for (int j = jb; j < je; ++j) {
        const int2 mtn = pmeta[j+1];     // prefetch next
        const int p = mt.x & 0xFFFFFF;
        const int et = ((unsigned)mt.x) >> 24;
        const float nm = __int_as_float(mt.y);
        const float4 cw = *(const float4*)(comp + et*NBAS);
        const float w0 = nm*cw.x, w1 = nm*cw.y, w2 = nm*cw.z, w3 = nm*cw.w;
        float hv[KS][8];
        if (IN_F32) {
            const float* hp = (const float*)hin + (size_t)p*DIN + g*8;
            #pragma unroll
            for (int ks = 0; ks < KS; ++ks) {
                float4 v0 = *(const float4*)(hp + ks*32);
                float4 v1 = *(const float4*)(hp + ks*32 + 4);
                hv[ks][0]=v0.x; hv[ks][1]=v0.y; hv[ks][2]=v0.z; hv[ks][3]=v0.w;
                hv[ks][4]=v1.x; hv[ks][5]=v1.y; hv[ks][6]=v1.z; hv[ks][7]=v1.w;
            }
        } else {
            const __bf16* hp = (const __bf16*)hin + (size_t)p*DIN + g*8;
            #pragma unroll
            for (int ks = 0; ks < KS; ++ks) {
                bf16x8 v = *(const bf16x8*)(hp + ks*32);
                #pragma unroll
                for (int c = 0; c < 8; ++c) hv[ks][c] = (float)v[c];
            }
        }
        #pragma unroll
        for (int ks = 0; ks < KS; ++ks) {
            #pragma unroll
            for (int c = 0; c < 8; ++c) {
                ka[0][ks][c] += w0*hv[ks][c];
                ka[1][ks][c] += w1*hv[ks][c];
                ka[2][ks][c] += w2*hv[ks][c];
                ka[3][ks][c] += w3*hv[ks][c];
            }
        }
        mt = mtn;
    }

    // ---- 4 basis MFMA phases ----
    #pragma unroll
    for (int b = 0; b < NBAS; ++b) {
        #pragma unroll
        for (int ks = 0; ks < KS; ++ks) {
            bf16x8 fa;
            #pragma unroll
            for (int c = 0; c < 8; ++c) fa[c] = (__bf16)ka[b][ks][c];
            #pragma unroll
            for (int nf = 0; nf < NF; ++nf) {
                bf16x8 fb = *(const bf16x8*)(Bt + ((size_t)b*DOUT + nf*16 + m)*DIN
                                             + ks*32 + g*8);
                acc[nf] = __builtin_amdgcn_mfma_f32_16x16x32_bf16(fa, fb, acc[nf], 0, 0, 0);
            }
        }
    }

    // ---- self-loop phase (A row = h[node], node perm-indexed) ----
    #pragma unroll
    for (int ks = 0; ks < KS; ++ks) {
        bf16x8 fa;
        if (IN_F32) {
            const float* hp = (const float*)hin + (size_t)node*DIN + ks*32 + g*8;
            float4 v0 = *(const float4*)hp;
            float4 v1 = *(const float4*)(hp + 4);
            fa[0]=(__bf16)v0.x; fa[1]=(__bf16)v0.y; fa[2]=(__bf16)v0.z; fa[3]=(__bf16)v0.w;
            fa[4]=(__bf16)v1.x; fa[5]=(__bf16)v1.y; fa[6]=(__bf16)v1.z; fa[7]=(__bf16)v1.w;
        } else {
            fa = *(const bf16x8*)((const __bf16*)hin + (size_t)node*DIN + ks*32 + g*8);
        }
        #pragma unroll
        for (int nf = 0; nf < NF; ++nf) {
            bf16x8 fb = *(const bf16x8*)(loopt + (size_t)(nf*16 + m)*DIN + ks*32 + g*8);
            acc[nf] = __builtin_amdgcn_mfma_f32_16x16x32_bf16(fa, fb, acc[nf], 0, 0, 0);
        }
    }

    // ---- epilogue: bias + activation + permuted store ----
    // D row g*4+ri maps to node perm[nb + g*4 + ri]
    int orow[4];
    #pragma unroll
    for (int ri = 0; ri < 4; ++ri) orow[ri] = perm[nb + g*4 + ri];
    #pragma unroll
    for (int nf = 0; nf < NF; ++nf) {
        const int col = nf*16 + m;
        const float bv = bias[col];
        #pragma unroll
        for (int ri = 0; ri < 4; ++ri) {
            float v = acc[nf][ri] + bv;
            if (ACT == 0) v = (v >= 0.f) ? v : NEG_SLOPE*v;
            else          v = 1.f/(1.f + __expf(-v));
            if (OUT_F32) ((float*)hout)[(size_t)orow[ri]*DOUT + col] = v;
            else         ((__bf16*)hout)[(size_t)orow[ri]*DOUT + col] = (__bf16)v;
        }
    }
}

// ======================================================================
// conv-transpose decoder + sigmoid, f32 logits, branchless phase taps.
// ======================================================================
__global__ __launch_bounds__(256) void k_convt_f32(const float* __restrict__ logits,
        const float* __restrict__ w, const float* __restrict__ cb, float* __restrict__ out) {
    __shared__ float s_w[49*32];   // [tap][c]
    const int tid = threadIdx.x;
    for (int idx = tid; idx < 49*32; idx += 256) {
        int tap = idx/32, c = idx%32;
        s_w[tap*32 + c] = w[c*49 + tap];
    }
    __syncthreads();
    int gidx = blockIdx.x*256 + tid;
    if (gidx >= B_GR*IWID*IWID) return;
    int b = gidx/(IWID*IWID);
    int rem = gidx%(IWID*IWID);
    int oy = rem/IWID, ox = rem%IWID;

    const int py = (oy+2)%3, qy = (oy+2)/3;
    const int px = (ox+2)%3, qx = (ox+2)/3;

    float acc = cb[0];
    #pragma unroll
    for (int sy = 0; sy < 3; ++sy) {
        const int ky = py + 3*sy;
        const int iy = qy - sy;
        if (ky > 6 || iy < 0 || iy >= GWID) continue;
        #pragma unroll
        for (int sx = 0; sx < 3; ++sx) {
            const int kx = px + 3*sx;
            const int ix = qx - sx;
            if (kx > 6 || ix < 0 || ix >= GWID) continue;
            const float4* xp = (const float4*)&logits[(((size_t)b*GWID + iy)*GWID + ix)*32];
            const float4* wp = (const float4*)&s_w[(ky*7 + kx)*32];
            #pragma unroll
            for (int c4 = 0; c4 < 8; ++c4) {
                float4 xv = xp[c4], wv = wp[c4];
                acc += xv.x*wv.x + xv.y*wv.y + xv.z*wv.z + xv.w*wv.w;
            }
        }
    }
    out[gidx] = 1.f/(1.f + __expf(-acc));
}

// ======================================================================
// host
// ======================================================================
extern "C" void kernel_launch(void* const* d_in, const int* in_sizes, int n_in,
                              void* d_out, int out_size, void* d_ws, size_t ws_size,
                              hipStream_t stream) {
    const float* features = (const float*)d_in[0];
    const int*   src      = (const int*)  d_in[1];
    const int*   dst      = (const int*)  d_in[2];
    const int*   etypes   = (const int*)  d_in[3];
    const float* norm     = (const float*)d_in[4];
    const float* bases0 = (const float*)d_in[5];
    const float* comp0  = (const float*)d_in[6];
    const float* loop0  = (const float*)d_in[7];
    const float* bias0  = (const float*)d_in[8];
    const float* bases1 = (const float*)d_in[9];
    const float* comp1  = (const float*)d_in[10];
    const float* loop1  = (const float*)d_in[11];
    const float* bias1  = (const float*)d_in[12];
    const float* bases2 = (const float*)d_in[13];
    const float* comp2  = (const float*)d_in[14];
    const float* loop2  = (const float*)d_in[15];
    const float* bias2  = (const float*)d_in[16];
    const float* conv_w = (const float*)d_in[17];
    const float* conv_b = (const float*)d_in[18];
    float* out = (float*)d_out;

    const int ebl = (E_EDGES + 255)/256;
    float* ws = (float*)d_ws;
    auto pad4 = [](size_t v){ return (v + 3) & ~(size_t)3; };

    // ---- workspace carve (float units), total ~53 MB ----
    size_t off = 0;
    __bf16* Bt0   = (__bf16*)(ws + off); off += (size_t)NBAS*32*64/2;
    __bf16* Bt1   = (__bf16*)(ws + off); off += (size_t)NBAS*64*64/2;
    __bf16* Bt2   = (__bf16*)(ws + off); off += (size_t)NBAS*64*32/2;
    __bf16* lt0   = (__bf16*)(ws + off); off += (size_t)64*32/2;
    __bf16* lt1   = (__bf16*)(ws + off); off += (size_t)64*64/2;
    __bf16* lt2   = (__bf16*)(ws + off); off += (size_t)32*64/2;
    __bf16* h1    = (__bf16*)(ws + off); off += (size_t)N_NODES*64/2;
    __bf16* h2    = (__bf16*)(ws + off); off += (size_t)N_NODES*64/2;
    float*  lg    = (float*)(ws + off);  off += (size_t)N_NODES*32;   // f32 logits
    int* rowptr   = (int*)(ws + off); off += pad4((size_t)N_NODES + 4);
    int* deg      = (int*)(ws + off); off += (size_t)N_NODES;   // becomes cursor
    int* bsum     = (int*)(ws + off); off += 512;
    int* perm     = (int*)(ws + off); off += (size_t)N_NODES;
    int* dhist    = (int*)(ws + off); off += DBUCK;
    int* dcur     = (int*)(ws + off); off += DBUCK;
    off = pad4(off);
    int2* pmeta   = (int2*)(ws + off); off += (size_t)(E_EDGES + 8)*2;  // +8 pad

    // ---- weight prep (transposed bf16 basis + loop tables) ----
    k_bases_t<<<(NBAS*32*64 + 255)/256, 256, 0, stream>>>(bases0, Bt0, 32, 64);
    k_bases_t<<<(NBAS*64*64 + 255)/256, 256, 0, stream>>>(bases1, Bt1, 64, 64);
    k_bases_t<<<(NBAS*64*32 + 255)/256, 256, 0, stream>>>(bases2, Bt2, 64, 32);
    k_loop_t<<<(32*64 + 255)/256, 256, 0, stream>>>(loop0, lt0, 32, 64);
    k_loop_t<<<(64*64 + 255)/256, 256, 0, stream>>>(loop1, lt1, 64, 64);
    k_loop_t<<<(64*32 + 255)/256, 256, 0, stream>>>(loop2, lt2, 64, 32);

    // ---- dst-CSR + single packed scatter (reused by all 3 layers) ----
    hipMemsetAsync(deg, 0, (size_t)N_NODES*sizeof(int), stream);
    k_deg  <<<ebl, 256, 0, stream>>>(dst, deg);
    k_scan1<<<SCAN_BLOCKS, 256, 0, stream>>>(deg, rowptr, bsum);
    k_scan2<<<1, 512, 0, stream>>>(bsum, rowptr);
    k_scan3<<<SCAN_BLOCKS, 256, 0, stream>>>(rowptr, bsum, deg);
    k_scatter_pack<<<ebl, 256, 0, stream>>>(src, dst, etypes, norm, deg, pmeta);

    // ---- degree-sorted node permutation ----
    hipMemsetAsync(dhist, 0, DBUCK*sizeof(int), stream);
    k_hist_deg   <<<SCAN_BLOCKS, 256, 0, stream>>>(rowptr, dhist);
    k_scan64     <<<1, 64, 0, stream>>>(dhist, dcur);
    k_scatter_perm<<<SCAN_BLOCKS, 256, 0, stream>>>(rowptr, dcur, perm);

    const int NROWT = N_NODES/64;   // 1800

    // ---- 3 fused basis layers (degree-sorted order) ----
    k_fusedb<32,64,0,1,0,4><<<NROWT, 256, 0, stream>>>(features, Bt0, lt0, bias0, comp0,
                                                       rowptr, pmeta, perm, h1);
    k_fusedb<64,64,0,0,0,3><<<NROWT, 256, 0, stream>>>(h1, Bt1, lt1, bias1, comp1,
                                                       rowptr, pmeta, perm, h2);
    k_fusedb<64,32,1,0,1,3><<<NROWT, 256, 0, stream>>>(h2, Bt2, lt2, bias2, comp2,
                                                       rowptr, pmeta, perm, lg);

    // ---- decoder (f32 logits) ----
    k_convt_f32<<<(B_GR*IWID*IWID + 255)/256, 256, 0, stream>>>(lg, conv_w, conv_b, out);
}

// Round 17
// 392.367 us; speedup vs baseline: 2.8999x; 2.8999x over previous
//
#include <hip/hip_runtime.h>
#include <hip/hip_bf16.h>

// Problem constants (match reference)
#define B_GR   128
#define GWID   30
#define IWID   90
#define C_IN   32
#define R_REL  8
#define NBAS   4
#define N_NODES (B_GR*GWID*GWID)   // 115200
#define E_EDGES (N_NODES*8)        // 921600
#define NEG_SLOPE 0.01f

#define SCAN_BLOCKS (N_NODES/256)  // 450
#define DBUCK 64
#define HG (DBUCK*SCAN_BLOCKS)     // 28800

typedef __attribute__((ext_vector_type(8))) __bf16 bf16x8;
typedef __attribute__((ext_vector_type(4))) float f32x4;

// ======================================================================
// Weight prep: Bt[b][c][k] = bf16(bases[b][k][c])  (B^T per base)
//              loopt[c][k] = bf16(loopw[k][c])
// ======================================================================
__global__ void k_bases_t(const float* __restrict__ bases, __bf16* __restrict__ Bt,
                          int din, int dout) {
    int idx = blockIdx.x*256 + threadIdx.x;
    int tot = NBAS*din*dout;
    if (idx >= tot) return;
    int b = idx/(dout*din), rem = idx%(dout*din);
    int c = rem/din, k = rem%din;
    Bt[idx] = (__bf16)bases[((size_t)b*din + k)*dout + c];
}
__global__ void k_loop_t(const float* __restrict__ loopw, __bf16* __restrict__ loopt,
                         int din, int dout) {
    int idx = blockIdx.x*256 + threadIdx.x;
    if (idx >= din*dout) return;
    int c = idx/din, k = idx%din;
    loopt[idx] = (__bf16)loopw[(size_t)k*dout + c];
}

// ======================================================================
// prep: plain dst-CSR, single scatter with fused 8B metadata per edge:
//   pmeta[j] = { src | et<<24 , bits(norm) }
// ======================================================================
__global__ void k_deg(const int* __restrict__ dst, int* __restrict__ deg) {
    int e = blockIdx.x*256 + threadIdx.x;
    if (e < E_EDGES) atomicAdd(&deg[dst[e]], 1);
}
__global__ __launch_bounds__(256) void k_scan1(const int* __restrict__ deg,
                                               int* __restrict__ rowptr,
                                               int* __restrict__ bsum) {
    __shared__ int s[256], s2[256];
    const int tid = threadIdx.x, gid = blockIdx.x*256 + tid;
    int v = deg[gid];
    s[tid] = v;
    __syncthreads();
    int* cur = s; int* nxt = s2;
    for (int d = 1; d < 256; d <<= 1) {
        int val = cur[tid];
        if (tid >= d) val += cur[tid - d];
        nxt[tid] = val;
        __syncthreads();
        int* t = cur; cur = nxt; nxt = t;
    }
    rowptr[gid] = cur[tid] - v;
    if (tid == 255) bsum[blockIdx.x] = cur[255];
}
__global__ __launch_bounds__(512) void k_scan2(int* __restrict__ bsum, int* __restrict__ rowptr) {
    __shared__ int s[512], s2[512];
    const int tid = threadIdx.x;
    int v = (tid < SCAN_BLOCKS) ? bsum[tid] : 0;
    s[tid] = v;
    __syncthreads();
    int* cur = s; int* nxt = s2;
    for (int d = 1; d < 512; d <<= 1) {
        int val = cur[tid];
        if (tid >= d) val += cur[tid - d];
        nxt[tid] = val;
        __syncthreads();
        int* t = cur; cur = nxt; nxt = t;
    }
    if (tid < SCAN_BLOCKS) bsum[tid] = cur[tid] - v;   // exclusive
    if (tid == 0) rowptr[N_NODES] = E_EDGES;
}
__global__ void k_scan3(int* __restrict__ rowptr, const int* __restrict__ bsum,
                        int* __restrict__ cursor) {
    int gid = blockIdx.x*256 + threadIdx.x;
    int v = rowptr[gid] + bsum[blockIdx.x];
    rowptr[gid] = v;
    cursor[gid] = v;
}
__global__ void k_scatter_pack(const int* __restrict__ src, const int* __restrict__ dst,
                               const int* __restrict__ et, const float* __restrict__ norm,
                               int* __restrict__ cursor, int2* __restrict__ pmeta) {
    int e = blockIdx.x*256 + threadIdx.x;
    if (e < E_EDGES) {
        int pos = atomicAdd(&cursor[dst[e]], 1);
        int2 m;
        m.x = src[e] | (et[e] << 24);
        m.y = __float_as_int(norm[e]);
        pmeta[pos] = m;
    }
}

// ======================================================================
// degree-sorted node permutation — CONTENTION-FREE (round-2 pattern):
// per-chunk LDS histogram -> scan of (bucket,chunk) table -> LDS-cursor scatter
// ======================================================================
__global__ __launch_bounds__(256) void k_hist_deg2(const int* __restrict__ rowptr,
                                                   int* __restrict__ hist_g) {
    __shared__ int h[DBUCK];
    const int tid = threadIdx.x, b = blockIdx.x;
    if (tid < DBUCK) h[tid] = 0;
    __syncthreads();
    const int n = b*256 + tid;
    int d = rowptr[n+1] - rowptr[n];
    d = d < DBUCK ? d : DBUCK-1;
    atomicAdd(&h[d], 1);                       // LDS atomic only
    __syncthreads();
    if (tid < DBUCK) hist_g[tid*SCAN_BLOCKS + b] = h[tid];   // bucket-major
}
__global__ __launch_bounds__(256) void k_scan_hg(int* __restrict__ hist_g) {
    __shared__ int s[256], s2[256];
    const int tid = threadIdx.x;
    const int per = (HG + 255)/256;            // 113
    const int beg = tid*per;
    const int end = (beg + per < HG) ? (beg + per) : HG;
    int loc = 0;
    for (int i = beg; i < end; ++i) loc += hist_g[i];
    s[tid] = loc;
    __syncthreads();
    int* cur = s; int* nxt = s2;
    for (int d = 1; d < 256; d <<= 1) {
        int v = cur[tid];
        if (tid >= d) v += cur[tid - d];
        nxt[tid] = v;
        __syncthreads();
        int* t = cur; cur = nxt; nxt = t;
    }
    int run = cur[tid] - loc;                  // exclusive prefix of this range
    for (int i = beg; i < end; ++i) { int v = hist_g[i]; hist_g[i] = run; run += v; }
}
__global__ __launch_bounds__(256) void k_scatter_perm2(const int* __restrict__ rowptr,
                                                       const int* __restrict__ hist_g,
                                                       int* __restrict__ perm) {
    __shared__ int cur[DBUCK];
    const int tid = threadIdx.x, b = blockIdx.x;
    if (tid < DBUCK) cur[tid] = hist_g[tid*SCAN_BLOCKS + b];
    __syncthreads();
    const int n = b*256 + tid;
    int d = rowptr[n+1] - rowptr[n];
    d = d < DBUCK ? d : DBUCK-1;
    int pos = atomicAdd(&cur[d], 1);           // LDS atomic only
    perm[pos] = n;
}

// ======================================================================
// Fused basis RGCN layer (R13 structure + degree-sorted node order):
//   hout[n] = act( sum_b (sum_e norm*comp[et,b]*h[src]) @ B_b + h[n]@loopw + bias )
// Wave owns 16 perm-consecutive nodes (near-equal degree). Single-pass
// gather, meta prefetch 1 ahead.
// Lane l: m=l&15 (row), g=l>>4 (K-subgroup). D: row g*4+ri, col nf*16+m.
// ======================================================================
template<int DIN, int DOUT, int ACT, int IN_F32, int OUT_F32, int MINW>
__global__ __launch_bounds__(256, MINW) void k_fusedb(
        const void* __restrict__ hin, const __bf16* __restrict__ Bt,
        const __bf16* __restrict__ loopt, const float* __restrict__ bias,
        const float* __restrict__ comp, const int* __restrict__ rowptr,
        const int2* __restrict__ pmeta, const int* __restrict__ perm,
        void* __restrict__ hout) {
    constexpr int KS = DIN/32;
    constexpr int NF = DOUT/16;
    const int tid = threadIdx.x;
    const int w = tid >> 6, l = tid & 63;
    const int m = l & 15, g = l >> 4;
    const int nb = blockIdx.x*64 + w*16;
    const int node = perm[nb + m];

    f32x4 acc[NF];
    #pragma unroll
    for (int nf = 0; nf < NF; ++nf) acc[nf] = (f32x4){0.f,0.f,0.f,0.f};

    // ---- single-pass gather into 4 basis accumulators ----
    float ka[NBAS][KS][8];
    #pragma unroll
    for (int b = 0; b < NBAS; ++b)
        #pragma unroll
        for (int ks = 0; ks < KS; ++ks)
            #pragma unroll
            for (int c = 0; c < 8; ++c) ka[b][ks][c] = 0.f;

    const int jb = rowptr[node], je = rowptr[node+1];
    int2 mt = pmeta[jb];                 // safe: pmeta padded
    for (int j = jb; j < je; ++j) {
        const int2 mtn = pmeta[j+1];     // prefetch next
        const int p = mt.x & 0xFFFFFF;
        const int et = ((unsigned)mt.x) >> 24;
        const float nm = __int_as_float(mt.y);
        const float4 cw = *(const float4*)(comp + et*NBAS);
        const float w0 = nm*cw.x, w1 = nm*cw.y, w2 = nm*cw.z, w3 = nm*cw.w;
        float hv[KS][8];
        if (IN_F32) {
            const float* hp = (const float*)hin + (size_t)p*DIN + g*8;
            #pragma unroll
            for (int ks = 0; ks < KS; ++ks) {
                float4 v0 = *(const float4*)(hp + ks*32);
                float4 v1 = *(const float4*)(hp + ks*32 + 4);
                hv[ks][0]=v0.x; hv[ks][1]=v0.y; hv[ks][2]=v0.z; hv[ks][3]=v0.w;
                hv[ks][4]=v1.x; hv[ks][5]=v1.y; hv[ks][6]=v1.z; hv[ks][7]=v1.w;
            }
        } else {
            const __bf16* hp = (const __bf16*)hin + (size_t)p*DIN + g*8;
            #pragma unroll
            for (int ks = 0; ks < KS; ++ks) {
                bf16x8 v = *(const bf16x8*)(hp + ks*32);
                #pragma unroll
                for (int c = 0; c < 8; ++c) hv[ks][c] = (float)v[c];
            }
        }
        #pragma unroll
        for (int ks = 0; ks < KS; ++ks) {
            #pragma unroll
            for (int c = 0; c < 8; ++c) {
                ka[0][ks][c] += w0*hv[ks][c];
                ka[1][ks][c] += w1*hv[ks][c];
                ka[2][ks][c] += w2*hv[ks][c];
                ka[3][ks][c] += w3*hv[ks][c];
            }
        }
        mt = mtn;
    }

    // ---- 4 basis MFMA phases ----
    #pragma unroll
    for (int b = 0; b < NBAS; ++b) {
        #pragma unroll
        for (int ks = 0; ks < KS; ++ks) {
            bf16x8 fa;
            #pragma unroll
            for (int c = 0; c < 8; ++c) fa[c] = (__bf16)ka[b][ks][c];
            #pragma unroll
            for (int nf = 0; nf < NF; ++nf) {
                bf16x8 fb = *(const bf16x8*)(Bt + ((size_t)b*DOUT + nf*16 + m)*DIN
                                             + ks*32 + g*8);
                acc[nf] = __builtin_amdgcn_mfma_f32_16x16x32_bf16(fa, fb, acc[nf], 0, 0, 0);
            }
        }
    }

    // ---- self-loop phase ----
    #pragma unroll
    for (int ks = 0; ks < KS; ++ks) {
        bf16x8 fa;
        if (IN_F32) {
            const float* hp = (const float*)hin + (size_t)node*DIN + ks*32 + g*8;
            float4 v0 = *(const float4*)hp;
            float4 v1 = *(const float4*)(hp + 4);
            fa[0]=(__bf16)v0.x; fa[1]=(__bf16)v0.y; fa[2]=(__bf16)v0.z; fa[3]=(__bf16)v0.w;
            fa[4]=(__bf16)v1.x; fa[5]=(__bf16)v1.y; fa[6]=(__bf16)v1.z; fa[7]=(__bf16)v1.w;
        } else {
            fa = *(const bf16x8*)((const __bf16*)hin + (size_t)node*DIN + ks*32 + g*8);
        }
        #pragma unroll
        for (int nf = 0; nf < NF; ++nf) {
            bf16x8 fb = *(const bf16x8*)(loopt + (size_t)(nf*16 + m)*DIN + ks*32 + g*8);
            acc[nf] = __builtin_amdgcn_mfma_f32_16x16x32_bf16(fa, fb, acc[nf], 0, 0, 0);
        }
    }

    // ---- epilogue: bias + activation + permuted store ----
    int orow[4];
    #pragma unroll
    for (int ri = 0; ri < 4; ++ri) orow[ri] = perm[nb + g*4 + ri];
    #pragma unroll
    for (int nf = 0; nf < NF; ++nf) {
        const int col = nf*16 + m;
        const float bv = bias[col];
        #pragma unroll
        for (int ri = 0; ri < 4; ++ri) {
            float v = acc[nf][ri] + bv;
            if (ACT == 0) v = (v >= 0.f) ? v : NEG_SLOPE*v;
            else          v = 1.f/(1.f + __expf(-v));
            if (OUT_F32) ((float*)hout)[(size_t)orow[ri]*DOUT + col] = v;
            else         ((__bf16*)hout)[(size_t)orow[ri]*DOUT + col] = (__bf16)v;
        }
    }
}

// ======================================================================
// conv-transpose decoder + sigmoid, f32 logits, branchless phase taps.
// ======================================================================
__global__ __launch_bounds__(256) void k_convt_f32(const float* __restrict__ logits,
        const float* __restrict__ w, const float* __restrict__ cb, float* __restrict__ out) {
    __shared__ float s_w[49*32];   // [tap][c]
    const int tid = threadIdx.x;
    for (int idx = tid; idx < 49*32; idx += 256) {
        int tap = idx/32, c = idx%32;
        s_w[tap*32 + c] = w[c*49 + tap];
    }
    __syncthreads();
    int gidx = blockIdx.x*256 + tid;
    if (gidx >= B_GR*IWID*IWID) return;
    int b = gidx/(IWID*IWID);
    int rem = gidx%(IWID*IWID);
    int oy = rem/IWID, ox = rem%IWID;

    const int py = (oy+2)%3, qy = (oy+2)/3;
    const int px = (ox+2)%3, qx = (ox+2)/3;

    float acc = cb[0];
    #pragma unroll
    for (int sy = 0; sy < 3; ++sy) {
        const int ky = py + 3*sy;
        const int iy = qy - sy;
        if (ky > 6 || iy < 0 || iy >= GWID) continue;
        #pragma unroll
        for (int sx = 0; sx < 3; ++sx) {
            const int kx = px + 3*sx;
            const int ix = qx - sx;
            if (kx > 6 || ix < 0 || ix >= GWID) continue;
            const float4* xp = (const float4*)&logits[(((size_t)b*GWID + iy)*GWID + ix)*32];
            const float4* wp = (const float4*)&s_w[(ky*7 + kx)*32];
            #pragma unroll
            for (int c4 = 0; c4 < 8; ++c4) {
                float4 xv = xp[c4], wv = wp[c4];
                acc += xv.x*wv.x + xv.y*wv.y + xv.z*wv.z + xv.w*wv.w;
            }
        }
    }
    out[gidx] = 1.f/(1.f + __expf(-acc));
}

// ======================================================================
// host
// ======================================================================
extern "C" void kernel_launch(void* const* d_in, const int* in_sizes, int n_in,
                              void* d_out, int out_size, void* d_ws, size_t ws_size,
                              hipStream_t stream) {
    const float* features = (const float*)d_in[0];
    const int*   src      = (const int*)  d_in[1];
    const int*   dst      = (const int*)  d_in[2];
    const int*   etypes   = (const int*)  d_in[3];
    const float* norm     = (const float*)d_in[4];
    const float* bases0 = (const float*)d_in[5];
    const float* comp0  = (const float*)d_in[6];
    const float* loop0  = (const float*)d_in[7];
    const float* bias0  = (const float*)d_in[8];
    const float* bases1 = (const float*)d_in[9];
    const float* comp1  = (const float*)d_in[10];
    const float* loop1  = (const float*)d_in[11];
    const float* bias1  = (const float*)d_in[12];
    const float* bases2 = (const float*)d_in[13];
    const float* comp2  = (const float*)d_in[14];
    const float* loop2  = (const float*)d_in[15];
    const float* bias2  = (const float*)d_in[16];
    const float* conv_w = (const float*)d_in[17];
    const float* conv_b = (const float*)d_in[18];
    float* out = (float*)d_out;

    const int ebl = (E_EDGES + 255)/256;
    float* ws = (float*)d_ws;
    auto pad4 = [](size_t v){ return (v + 3) & ~(size_t)3; };

    // ---- workspace carve (float units), total ~53 MB ----
    size_t off = 0;
    __bf16* Bt0   = (__bf16*)(ws + off); off += (size_t)NBAS*32*64/2;
    __bf16* Bt1   = (__bf16*)(ws + off); off += (size_t)NBAS*64*64/2;
    __bf16* Bt2   = (__bf16*)(ws + off); off += (size_t)NBAS*64*32/2;
    __bf16* lt0   = (__bf16*)(ws + off); off += (size_t)64*32/2;
    __bf16* lt1   = (__bf16*)(ws + off); off += (size_t)64*64/2;
    __bf16* lt2   = (__bf16*)(ws + off); off += (size_t)32*64/2;
    __bf16* h1    = (__bf16*)(ws + off); off += (size_t)N_NODES*64/2;
    __bf16* h2    = (__bf16*)(ws + off); off += (size_t)N_NODES*64/2;
    float*  lg    = (float*)(ws + off);  off += (size_t)N_NODES*32;   // f32 logits
    int* rowptr   = (int*)(ws + off); off += pad4((size_t)N_NODES + 4);
    int* deg      = (int*)(ws + off); off += (size_t)N_NODES;   // becomes cursor
    int* bsum     = (int*)(ws + off); off += 512;
    int* perm     = (int*)(ws + off); off += (size_t)N_NODES;
    int* hist_g   = (int*)(ws + off); off += HG;
    off = pad4(off);
    int2* pmeta   = (int2*)(ws + off); off += (size_t)(E_EDGES + 8)*2;  // +8 pad

    // ---- weight prep (transposed bf16 basis + loop tables) ----
    k_bases_t<<<(NBAS*32*64 + 255)/256, 256, 0, stream>>>(bases0, Bt0, 32, 64);
    k_bases_t<<<(NBAS*64*64 + 255)/256, 256, 0, stream>>>(bases1, Bt1, 64, 64);
    k_bases_t<<<(NBAS*64*32 + 255)/256, 256, 0, stream>>>(bases2, Bt2, 64, 32);
    k_loop_t<<<(32*64 + 255)/256, 256, 0, stream>>>(loop0, lt0, 32, 64);
    k_loop_t<<<(64*64 + 255)/256, 256, 0, stream>>>(loop1, lt1, 64, 64);
    k_loop_t<<<(64*32 + 255)/256, 256, 0, stream>>>(loop2, lt2, 64, 32);

    // ---- dst-CSR + single packed scatter (reused by all 3 layers) ----
    hipMemsetAsync(deg, 0, (size_t)N_NODES*sizeof(int), stream);
    k_deg  <<<ebl, 256, 0, stream>>>(dst, deg);
    k_scan1<<<SCAN_BLOCKS, 256, 0, stream>>>(deg, rowptr, bsum);
    k_scan2<<<1, 512, 0, stream>>>(bsum, rowptr);
    k_scan3<<<SCAN_BLOCKS, 256, 0, stream>>>(rowptr, bsum, deg);
    k_scatter_pack<<<ebl, 256, 0, stream>>>(src, dst, etypes, norm, deg, pmeta);

    // ---- degree-sorted node permutation (contention-free) ----
    k_hist_deg2   <<<SCAN_BLOCKS, 256, 0, stream>>>(rowptr, hist_g);
    k_scan_hg     <<<1, 256, 0, stream>>>(hist_g);
    k_scatter_perm2<<<SCAN_BLOCKS, 256, 0, stream>>>(rowptr, hist_g, perm);

    const int NROWT = N_NODES/64;   // 1800

    // ---- 3 fused basis layers (degree-sorted order) ----
    k_fusedb<32,64,0,1,0,4><<<NROWT, 256, 0, stream>>>(features, Bt0, lt0, bias0, comp0,
                                                       rowptr, pmeta, perm, h1);
    k_fusedb<64,64,0,0,0,3><<<NROWT, 256, 0, stream>>>(h1, Bt1, lt1, bias1, comp1,
                                                       rowptr, pmeta, perm, h2);
    k_fusedb<64,32,1,0,1,3><<<NROWT, 256, 0, stream>>>(h2, Bt2, lt2, bias2, comp2,
                                                       rowptr, pmeta, perm, lg);

    // ---- decoder (f32 logits) ----
    k_convt_f32<<<(B_GR*IWID*IWID + 255)/256, 256, 0, stream>>>(lg, conv_w, conv_b, out);
}

// Round 18
// 353.427 us; speedup vs baseline: 3.2194x; 1.1102x over previous
//
#include <hip/hip_runtime.h>
#include <hip/hip_bf16.h>

// Problem constants (match reference)
#define B_GR   128
#define GWID   30
#define IWID   90
#define C_IN   32
#define R_REL  8
#define NBAS   4
#define N_NODES (B_GR*GWID*GWID)   // 115200
#define E_EDGES (N_NODES*8)        // 921600
#define NEG_SLOPE 0.01f

#define SCAN_BLOCKS (N_NODES/256)  // 450

typedef __attribute__((ext_vector_type(8))) __bf16 bf16x8;
typedef __attribute__((ext_vector_type(4))) float f32x4;

// ======================================================================
// Weight prep: Bt[b][c][k] = bf16(bases[b][k][c])  (B^T per base)
//              loopt[c][k] = bf16(loopw[k][c])
// ======================================================================
__global__ void k_bases_t(const float* __restrict__ bases, __bf16* __restrict__ Bt,
                          int din, int dout) {
    int idx = blockIdx.x*256 + threadIdx.x;
    int tot = NBAS*din*dout;
    if (idx >= tot) return;
    int b = idx/(dout*din), rem = idx%(dout*din);
    int c = rem/din, k = rem%din;
    Bt[idx] = (__bf16)bases[((size_t)b*din + k)*dout + c];
}
__global__ void k_loop_t(const float* __restrict__ loopw, __bf16* __restrict__ loopt,
                         int din, int dout) {
    int idx = blockIdx.x*256 + threadIdx.x;
    if (idx >= din*dout) return;
    int c = idx/din, k = idx%din;
    loopt[idx] = (__bf16)loopw[(size_t)k*dout + c];
}

// ======================================================================
// prep: plain dst-CSR, single scatter with fused 8B metadata per edge:
//   pmeta[j] = { src | et<<24 , bits(norm) }
// ======================================================================
__global__ void k_deg(const int* __restrict__ dst, int* __restrict__ deg) {
    int e = blockIdx.x*256 + threadIdx.x;
    if (e < E_EDGES) atomicAdd(&deg[dst[e]], 1);
}
__global__ __launch_bounds__(256) void k_scan1(const int* __restrict__ deg,
                                               int* __restrict__ rowptr,
                                               int* __restrict__ bsum) {
    __shared__ int s[256], s2[256];
    const int tid = threadIdx.x, gid = blockIdx.x*256 + tid;
    int v = deg[gid];
    s[tid] = v;
    __syncthreads();
    int* cur = s; int* nxt = s2;
    for (int d = 1; d < 256; d <<= 1) {
        int val = cur[tid];
        if (tid >= d) val += cur[tid - d];
        nxt[tid] = val;
        __syncthreads();
        int* t = cur; cur = nxt; nxt = t;
    }
    rowptr[gid] = cur[tid] - v;
    if (tid == 255) bsum[blockIdx.x] = cur[255];
}
__global__ __launch_bounds__(512) void k_scan2(int* __restrict__ bsum, int* __restrict__ rowptr) {
    __shared__ int s[512], s2[512];
    const int tid = threadIdx.x;
    int v = (tid < SCAN_BLOCKS) ? bsum[tid] : 0;
    s[tid] = v;
    __syncthreads();
    int* cur = s; int* nxt = s2;
    for (int d = 1; d < 512; d <<= 1) {
        int val = cur[tid];
        if (tid >= d) val += cur[tid - d];
        nxt[tid] = val;
        __syncthreads();
        int* t = cur; cur = nxt; nxt = t;
    }
    if (tid < SCAN_BLOCKS) bsum[tid] = cur[tid] - v;   // exclusive
    if (tid == 0) rowptr[N_NODES] = E_EDGES;
}
__global__ void k_scan3(int* __restrict__ rowptr, const int* __restrict__ bsum,
                        int* __restrict__ cursor) {
    int gid = blockIdx.x*256 + threadIdx.x;
    int v = rowptr[gid] + bsum[blockIdx.x];
    rowptr[gid] = v;
    cursor[gid] = v;
}
__global__ void k_scatter_pack(const int* __restrict__ src, const int* __restrict__ dst,
                               const int* __restrict__ et, const float* __restrict__ norm,
                               int* __restrict__ cursor, int2* __restrict__ pmeta) {
    int e = blockIdx.x*256 + threadIdx.x;
    if (e < E_EDGES) {
        int pos = atomicAdd(&cursor[dst[e]], 1);
        int2 m;
        m.x = src[e] | (et[e] << 24);
        m.y = __float_as_int(norm[e]);
        pmeta[pos] = m;
    }
}

// ======================================================================
// Fused basis RGCN layer, R13 form (used for layer 0, DIN=32):
// single-pass gather, meta prefetch, 4 basis MFMA phases + self-loop.
// ======================================================================
template<int DIN, int DOUT, int ACT, int IN_F32, int OUT_F32, int MINW>
__global__ __launch_bounds__(256, MINW) void k_fusedb(
        const void* __restrict__ hin, const __bf16* __restrict__ Bt,
        const __bf16* __restrict__ loopt, const float* __restrict__ bias,
        const float* __restrict__ comp, const int* __restrict__ rowptr,
        const int2* __restrict__ pmeta, void* __restrict__ hout) {
    constexpr int KS = DIN/32;
    constexpr int NF = DOUT/16;
    const int tid = threadIdx.x;
    const int w = tid >> 6, l = tid & 63;
    const int m = l & 15, g = l >> 4;
    const int nb = blockIdx.x*64 + w*16;
    const int node = nb + m;

    f32x4 acc[NF];
    #pragma unroll
    for (int nf = 0; nf < NF; ++nf) acc[nf] = (f32x4){0.f,0.f,0.f,0.f};

    float ka[NBAS][KS][8];
    #pragma unroll
    for (int b = 0; b < NBAS; ++b)
        #pragma unroll
        for (int ks = 0; ks < KS; ++ks)
            #pragma unroll
            for (int c = 0; c < 8; ++c) ka[b][ks][c] = 0.f;

    const int jb = rowptr[node], je = rowptr[node+1];
    int2 mt = pmeta[jb];
    for (int j = jb; j < je; ++j) {
        const int2 mtn = pmeta[j+1];
        const int p = mt.x & 0xFFFFFF;
        const int et = ((unsigned)mt.x) >> 24;
        const float nm = __int_as_float(mt.y);
        const float4 cw = *(const float4*)(comp + et*NBAS);
        const float w0 = nm*cw.x, w1 = nm*cw.y, w2 = nm*cw.z, w3 = nm*cw.w;
        float hv[KS][8];
        if (IN_F32) {
            const float* hp = (const float*)hin + (size_t)p*DIN + g*8;
            #pragma unroll
            for (int ks = 0; ks < KS; ++ks) {
                float4 v0 = *(const float4*)(hp + ks*32);
                float4 v1 = *(const float4*)(hp + ks*32 + 4);
                hv[ks][0]=v0.x; hv[ks][1]=v0.y; hv[ks][2]=v0.z; hv[ks][3]=v0.w;
                hv[ks][4]=v1.x; hv[ks][5]=v1.y; hv[ks][6]=v1.z; hv[ks][7]=v1.w;
            }
        } else {
            const __bf16* hp = (const __bf16*)hin + (size_t)p*DIN + g*8;
            #pragma unroll
            for (int ks = 0; ks < KS; ++ks) {
                bf16x8 v = *(const bf16x8*)(hp + ks*32);
                #pragma unroll
                for (int c = 0; c < 8; ++c) hv[ks][c] = (float)v[c];
            }
        }
        #pragma unroll
        for (int ks = 0; ks < KS; ++ks) {
            #pragma unroll
            for (int c = 0; c < 8; ++c) {
                ka[0][ks][c] += w0*hv[ks][c];
                ka[1][ks][c] += w1*hv[ks][c];
                ka[2][ks][c] += w2*hv[ks][c];
                ka[3][ks][c] += w3*hv[ks][c];
            }
        }
        mt = mtn;
    }

    #pragma unroll
    for (int b = 0; b < NBAS; ++b) {
        #pragma unroll
        for (int ks = 0; ks < KS; ++ks) {
            bf16x8 fa;
            #pragma unroll
            for (int c = 0; c < 8; ++c) fa[c] = (__bf16)ka[b][ks][c];
            #pragma unroll
            for (int nf = 0; nf < NF; ++nf) {
                bf16x8 fb = *(const bf16x8*)(Bt + ((size_t)b*DOUT + nf*16 + m)*DIN
                                             + ks*32 + g*8);
                acc[nf] = __builtin_amdgcn_mfma_f32_16x16x32_bf16(fa, fb, acc[nf], 0, 0, 0);
            }
        }
    }

    #pragma unroll
    for (int ks = 0; ks < KS; ++ks) {
        bf16x8 fa;
        if (IN_F32) {
            const float* hp = (const float*)hin + (size_t)node*DIN + ks*32 + g*8;
            float4 v0 = *(const float4*)hp;
            float4 v1 = *(const float4*)(hp + 4);
            fa[0]=(__bf16)v0.x; fa[1]=(__bf16)v0.y; fa[2]=(__bf16)v0.z; fa[3]=(__bf16)v0.w;
            fa[4]=(__bf16)v1.x; fa[5]=(__bf16)v1.y; fa[6]=(__bf16)v1.z; fa[7]=(__bf16)v1.w;
        } else {
            fa = *(const bf16x8*)((const __bf16*)hin + (size_t)node*DIN + ks*32 + g*8);
        }
        #pragma unroll
        for (int nf = 0; nf < NF; ++nf) {
            bf16x8 fb = *(const bf16x8*)(loopt + (size_t)(nf*16 + m)*DIN + ks*32 + g*8);
            acc[nf] = __builtin_amdgcn_mfma_f32_16x16x32_bf16(fa, fb, acc[nf], 0, 0, 0);
        }
    }

    #pragma unroll
    for (int nf = 0; nf < NF; ++nf) {
        const int col = nf*16 + m;
        const float bv = bias[col];
        #pragma unroll
        for (int ri = 0; ri < 4; ++ri) {
            const int orow = nb + g*4 + ri;
            float v = acc[nf][ri] + bv;
            if (ACT == 0) v = (v >= 0.f) ? v : NEG_SLOPE*v;
            else          v = 1.f/(1.f + __expf(-v));
            if (OUT_F32) ((float*)hout)[(size_t)orow*DOUT + col] = v;
            else         ((__bf16*)hout)[(size_t)orow*DOUT + col] = (__bf16)v;
        }
    }
}

// ======================================================================
// K-SPLIT fused basis layer (DIN=64 layers): wave PAIR shares 16 nodes,
// wave kh gathers only its 32-col K-half (16B/edge) -> ka 32 regs, hv 8
// -> ~88 unified regs -> ~5 waves/SIMD (vs 3). Both waves MFMA K-partials
// of the SAME output tile; kh=1 exports acc via LDS; kh=0 combines,
// adds its self-loop half (kh=0) + kh=1's half comes via the partial,
// applies bias/act, stores.
// Block = 256 thr = 4 waves = 2 pairs = 32 nodes.
// ======================================================================
template<int DOUT, int ACT, int OUT_F32, int MINW>
__global__ __launch_bounds__(256, MINW) void k_fusedb_ks(
        const __bf16* __restrict__ hin, const __bf16* __restrict__ Bt,
        const __bf16* __restrict__ loopt, const float* __restrict__ bias,
        const float* __restrict__ comp, const int* __restrict__ rowptr,
        const int2* __restrict__ pmeta, void* __restrict__ hout) {
    constexpr int DIN = 64;
    constexpr int NF = DOUT/16;
    __shared__ float lds_acc[2][NF*4][64];
    const int tid = threadIdx.x;
    const int w = tid >> 6, l = tid & 63;
    const int pair = w >> 1, kh = w & 1;
    const int m = l & 15, g = l >> 4;
    const int nb = blockIdx.x*32 + pair*16;
    const int node = nb + m;
    const int kcol = kh*32 + g*8;      // this lane's 8-col slice

    f32x4 acc[NF];
    #pragma unroll
    for (int nf = 0; nf < NF; ++nf) acc[nf] = (f32x4){0.f,0.f,0.f,0.f};

    float ka[NBAS][8];
    #pragma unroll
    for (int b = 0; b < NBAS; ++b)
        #pragma unroll
        for (int c = 0; c < 8; ++c) ka[b][c] = 0.f;

    const int jb = rowptr[node], je = rowptr[node+1];
    int2 mt = pmeta[jb];
    for (int j = jb; j < je; ++j) {
        const int2 mtn = pmeta[j+1];
        const int p = mt.x & 0xFFFFFF;
        const int et = ((unsigned)mt.x) >> 24;
        const float nm = __int_as_float(mt.y);
        const float4 cw = *(const float4*)(comp + et*NBAS);
        const float w0 = nm*cw.x, w1 = nm*cw.y, w2 = nm*cw.z, w3 = nm*cw.w;
        bf16x8 v = *(const bf16x8*)(hin + (size_t)p*DIN + kcol);
        #pragma unroll
        for (int c = 0; c < 8; ++c) {
            const float hv = (float)v[c];
            ka[0][c] += w0*hv;
            ka[1][c] += w1*hv;
            ka[2][c] += w2*hv;
            ka[3][c] += w3*hv;
        }
        mt = mtn;
    }

    // basis MFMA K-partials (this wave covers K cols kh*32 .. kh*32+31)
    #pragma unroll
    for (int b = 0; b < NBAS; ++b) {
        bf16x8 fa;
        #pragma unroll
        for (int c = 0; c < 8; ++c) fa[c] = (__bf16)ka[b][c];
        #pragma unroll
        for (int nf = 0; nf < NF; ++nf) {
            bf16x8 fb = *(const bf16x8*)(Bt + ((size_t)b*DOUT + nf*16 + m)*DIN + kcol);
            acc[nf] = __builtin_amdgcn_mfma_f32_16x16x32_bf16(fa, fb, acc[nf], 0, 0, 0);
        }
    }
    // self-loop K-half (each wave does its half -> sums in combine)
    {
        bf16x8 fa = *(const bf16x8*)(hin + (size_t)node*DIN + kcol);
        #pragma unroll
        for (int nf = 0; nf < NF; ++nf) {
            bf16x8 fb = *(const bf16x8*)(loopt + (size_t)(nf*16 + m)*DIN + kcol);
            acc[nf] = __builtin_amdgcn_mfma_f32_16x16x32_bf16(fa, fb, acc[nf], 0, 0, 0);
        }
    }

    // kh=1 exports partial acc
    if (kh == 1) {
        #pragma unroll
        for (int nf = 0; nf < NF; ++nf)
            #pragma unroll
            for (int ri = 0; ri < 4; ++ri)
                lds_acc[pair][nf*4 + ri][l] = acc[nf][ri];
    }
    __syncthreads();

    // kh=0 combines + epilogue
    if (kh == 0) {
        #pragma unroll
        for (int nf = 0; nf < NF; ++nf) {
            const int col = nf*16 + m;
            const float bv = bias[col];
            #pragma unroll
            for (int ri = 0; ri < 4; ++ri) {
                float v = acc[nf][ri] + lds_acc[pair][nf*4 + ri][l] + bv;
                if (ACT == 0) v = (v >= 0.f) ? v : NEG_SLOPE*v;
                else          v = 1.f/(1.f + __expf(-v));
                const int orow = nb + g*4 + ri;
                if (OUT_F32) ((float*)hout)[(size_t)orow*DOUT + col] = v;
                else         ((__bf16*)hout)[(size_t)orow*DOUT + col] = (__bf16)v;
            }
        }
    }
}

// ======================================================================
// conv-transpose decoder + sigmoid, f32 logits, branchless phase taps.
// ======================================================================
__global__ __launch_bounds__(256) void k_convt_f32(const float* __restrict__ logits,
        const float* __restrict__ w, const float* __restrict__ cb, float* __restrict__ out) {
    __shared__ float s_w[49*32];   // [tap][c]
    const int tid = threadIdx.x;
    for (int idx = tid; idx < 49*32; idx += 256) {
        int tap = idx/32, c = idx%32;
        s_w[tap*32 + c] = w[c*49 + tap];
    }
    __syncthreads();
    int gidx = blockIdx.x*256 + tid;
    if (gidx >= B_GR*IWID*IWID) return;
    int b = gidx/(IWID*IWID);
    int rem = gidx%(IWID*IWID);
    int oy = rem/IWID, ox = rem%IWID;

    const int py = (oy+2)%3, qy = (oy+2)/3;
    const int px = (ox+2)%3, qx = (ox+2)/3;

    float acc = cb[0];
    #pragma unroll
    for (int sy = 0; sy < 3; ++sy) {
        const int ky = py + 3*sy;
        const int iy = qy - sy;
        if (ky > 6 || iy < 0 || iy >= GWID) continue;
        #pragma unroll
        for (int sx = 0; sx < 3; ++sx) {
            const int kx = px + 3*sx;
            const int ix = qx - sx;
            if (kx > 6 || ix < 0 || ix >= GWID) continue;
            const float4* xp = (const float4*)&logits[(((size_t)b*GWID + iy)*GWID + ix)*32];
            const float4* wp = (const float4*)&s_w[(ky*7 + kx)*32];
            #pragma unroll
            for (int c4 = 0; c4 < 8; ++c4) {
                float4 xv = xp[c4], wv = wp[c4];
                acc += xv.x*wv.x + xv.y*wv.y + xv.z*wv.z + xv.w*wv.w;
            }
        }
    }
    out[gidx] = 1.f/(1.f + __expf(-acc));
}

// ======================================================================
// host
// ======================================================================
extern "C" void kernel_launch(void* const* d_in, const int* in_sizes, int n_in,
                              void* d_out, int out_size, void* d_ws, size_t ws_size,
                              hipStream_t stream) {
    const float* features = (const float*)d_in[0];
    const int*   src      = (const int*)  d_in[1];
    const int*   dst      = (const int*)  d_in[2];
    const int*   etypes   = (const int*)  d_in[3];
    const float* norm     = (const float*)d_in[4];
    const float* bases0 = (const float*)d_in[5];
    const float* comp0  = (const float*)d_in[6];
    const float* loop0  = (const float*)d_in[7];
    const float* bias0  = (const float*)d_in[8];
    const float* bases1 = (const float*)d_in[9];
    const float* comp1  = (const float*)d_in[10];
    const float* loop1  = (const float*)d_in[11];
    const float* bias1  = (const float*)d_in[12];
    const float* bases2 = (const float*)d_in[13];
    const float* comp2  = (const float*)d_in[14];
    const float* loop2  = (const float*)d_in[15];
    const float* bias2  = (const float*)d_in[16];
    const float* conv_w = (const float*)d_in[17];
    const float* conv_b = (const float*)d_in[18];
    float* out = (float*)d_out;

    const int ebl = (E_EDGES + 255)/256;
    float* ws = (float*)d_ws;
    auto pad4 = [](size_t v){ return (v + 3) & ~(size_t)3; };

    // ---- workspace carve (float units), total ~52 MB ----
    size_t off = 0;
    __bf16* Bt0   = (__bf16*)(ws + off); off += (size_t)NBAS*32*64/2;
    __bf16* Bt1   = (__bf16*)(ws + off); off += (size_t)NBAS*64*64/2;
    __bf16* Bt2   = (__bf16*)(ws + off); off += (size_t)NBAS*64*32/2;
    __bf16* lt0   = (__bf16*)(ws + off); off += (size_t)64*32/2;
    __bf16* lt1   = (__bf16*)(ws + off); off += (size_t)64*64/2;
    __bf16* lt2   = (__bf16*)(ws + off); off += (size_t)32*64/2;
    __bf16* h1    = (__bf16*)(ws + off); off += (size_t)N_NODES*64/2;
    __bf16* h2    = (__bf16*)(ws + off); off += (size_t)N_NODES*64/2;
    float*  lg    = (float*)(ws + off);  off += (size_t)N_NODES*32;   // f32 logits
    int* rowptr   = (int*)(ws + off); off += pad4((size_t)N_NODES + 4);
    int* deg      = (int*)(ws + off); off += (size_t)N_NODES;   // becomes cursor
    int* bsum     = (int*)(ws + off); off += 512;
    int2* pmeta   = (int2*)(ws + off); off += (size_t)(E_EDGES + 8)*2;  // +8 pad

    // ---- weight prep (transposed bf16 basis + loop tables) ----
    k_bases_t<<<(NBAS*32*64 + 255)/256, 256, 0, stream>>>(bases0, Bt0, 32, 64);
    k_bases_t<<<(NBAS*64*64 + 255)/256, 256, 0, stream>>>(bases1, Bt1, 64, 64);
    k_bases_t<<<(NBAS*64*32 + 255)/256, 256, 0, stream>>>(bases2, Bt2, 64, 32);
    k_loop_t<<<(32*64 + 255)/256, 256, 0, stream>>>(loop0, lt0, 32, 64);
    k_loop_t<<<(64*64 + 255)/256, 256, 0, stream>>>(loop1, lt1, 64, 64);
    k_loop_t<<<(64*32 + 255)/256, 256, 0, stream>>>(loop2, lt2, 64, 32);

    // ---- dst-CSR + single packed scatter (reused by all 3 layers) ----
    hipMemsetAsync(deg, 0, (size_t)N_NODES*sizeof(int), stream);
    k_deg  <<<ebl, 256, 0, stream>>>(dst, deg);
    k_scan1<<<SCAN_BLOCKS, 256, 0, stream>>>(deg, rowptr, bsum);
    k_scan2<<<1, 512, 0, stream>>>(bsum, rowptr);
    k_scan3<<<SCAN_BLOCKS, 256, 0, stream>>>(rowptr, bsum, deg);
    k_scatter_pack<<<ebl, 256, 0, stream>>>(src, dst, etypes, norm, deg, pmeta);

    const int NROWT = N_NODES/64;    // 1800 (layer-0 kernel)
    const int NSPL  = N_NODES/32;    // 3600 (K-split kernels)

    // ---- 3 fused basis layers ----
    k_fusedb<32,64,0,1,0,4><<<NROWT, 256, 0, stream>>>(features, Bt0, lt0, bias0, comp0,
                                                       rowptr, pmeta, h1);
    k_fusedb_ks<64,0,0,5><<<NSPL, 256, 0, stream>>>(h1, Bt1, lt1, bias1, comp1,
                                                    rowptr, pmeta, h2);
    k_fusedb_ks<32,1,1,5><<<NSPL, 256, 0, stream>>>(h2, Bt2, lt2, bias2, comp2,
                                                    rowptr, pmeta, lg);

    // ---- decoder (f32 logits) ----
    k_convt_f32<<<(B_GR*IWID*IWID + 255)/256, 256, 0, stream>>>(lg, conv_w, conv_b, out);
}

// Round 19
// 327.787 us; speedup vs baseline: 3.4713x; 1.0782x over previous
//
#include <hip/hip_runtime.h>
#include <hip/hip_bf16.h>

// Problem constants (match reference)
#define B_GR   128
#define GWID   30
#define IWID   90
#define C_IN   32
#define R_REL  8
#define NBAS   4
#define N_NODES (B_GR*GWID*GWID)   // 115200
#define E_EDGES (N_NODES*8)        // 921600
#define NEG_SLOPE 0.01f

#define SCAN_BLOCKS (N_NODES/256)  // 450

typedef __attribute__((ext_vector_type(8))) __bf16 bf16x8;
typedef __attribute__((ext_vector_type(4))) float f32x4;

// ======================================================================
// Weight prep: Bt[b][c][k] = bf16(bases[b][k][c])  (B^T per base)
//              loopt[c][k] = bf16(loopw[k][c])
// ======================================================================
__global__ void k_bases_t(const float* __restrict__ bases, __bf16* __restrict__ Bt,
                          int din, int dout) {
    int idx = blockIdx.x*256 + threadIdx.x;
    int tot = NBAS*din*dout;
    if (idx >= tot) return;
    int b = idx/(dout*din), rem = idx%(dout*din);
    int c = rem/din, k = rem%din;
    Bt[idx] = (__bf16)bases[((size_t)b*din + k)*dout + c];
}
__global__ void k_loop_t(const float* __restrict__ loopw, __bf16* __restrict__ loopt,
                         int din, int dout) {
    int idx = blockIdx.x*256 + threadIdx.x;
    if (idx >= din*dout) return;
    int c = idx/din, k = idx%din;
    loopt[idx] = (__bf16)loopw[(size_t)k*dout + c];
}
// features f32 -> bf16 (one streaming pass; halves L0 gather line-misses)
__global__ void k_feat2bf(const float* __restrict__ f, __bf16* __restrict__ fb) {
    int i = blockIdx.x*256 + threadIdx.x;   // processes 8 elems
    if (i >= N_NODES*C_IN/8) return;
    const float4* p = (const float4*)(f + (size_t)i*8);
    float4 a = p[0], b = p[1];
    bf16x8 o;
    o[0]=(__bf16)a.x; o[1]=(__bf16)a.y; o[2]=(__bf16)a.z; o[3]=(__bf16)a.w;
    o[4]=(__bf16)b.x; o[5]=(__bf16)b.y; o[6]=(__bf16)b.z; o[7]=(__bf16)b.w;
    *(bf16x8*)(fb + (size_t)i*8) = o;
}

// ======================================================================
// prep: plain dst-CSR, single scatter with fused 8B metadata per edge:
//   pmeta[j] = { src | et<<24 , bits(norm) }
// ======================================================================
__global__ void k_deg(const int* __restrict__ dst, int* __restrict__ deg) {
    int e = blockIdx.x*256 + threadIdx.x;
    if (e < E_EDGES) atomicAdd(&deg[dst[e]], 1);
}
__global__ __launch_bounds__(256) void k_scan1(const int* __restrict__ deg,
                                               int* __restrict__ rowptr,
                                               int* __restrict__ bsum) {
    __shared__ int s[256], s2[256];
    const int tid = threadIdx.x, gid = blockIdx.x*256 + tid;
    int v = deg[gid];
    s[tid] = v;
    __syncthreads();
    int* cur = s; int* nxt = s2;
    for (int d = 1; d < 256; d <<= 1) {
        int val = cur[tid];
        if (tid >= d) val += cur[tid - d];
        nxt[tid] = val;
        __syncthreads();
        int* t = cur; cur = nxt; nxt = t;
    }
    rowptr[gid] = cur[tid] - v;
    if (tid == 255) bsum[blockIdx.x] = cur[255];
}
__global__ __launch_bounds__(512) void k_scan2(int* __restrict__ bsum, int* __restrict__ rowptr) {
    __shared__ int s[512], s2[512];
    const int tid = threadIdx.x;
    int v = (tid < SCAN_BLOCKS) ? bsum[tid] : 0;
    s[tid] = v;
    __syncthreads();
    int* cur = s; int* nxt = s2;
    for (int d = 1; d < 512; d <<= 1) {
        int val = cur[tid];
        if (tid >= d) val += cur[tid - d];
        nxt[tid] = val;
        __syncthreads();
        int* t = cur; cur = nxt; nxt = t;
    }
    if (tid < SCAN_BLOCKS) bsum[tid] = cur[tid] - v;   // exclusive
    if (tid == 0) rowptr[N_NODES] = E_EDGES;
}
__global__ void k_scan3(int* __restrict__ rowptr, const int* __restrict__ bsum,
                        int* __restrict__ cursor) {
    int gid = blockIdx.x*256 + threadIdx.x;
    int v = rowptr[gid] + bsum[blockIdx.x];
    rowptr[gid] = v;
    cursor[gid] = v;
}
__global__ void k_scatter_pack(const int* __restrict__ src, const int* __restrict__ dst,
                               const int* __restrict__ et, const float* __restrict__ norm,
                               int* __restrict__ cursor, int2* __restrict__ pmeta) {
    int e = blockIdx.x*256 + threadIdx.x;
    if (e < E_EDGES) {
        int pos = atomicAdd(&cursor[dst[e]], 1);
        int2 m;
        m.x = src[e] | (et[e] << 24);
        m.y = __float_as_int(norm[e]);
        pmeta[pos] = m;
    }
}

// ======================================================================
// Fused basis RGCN layer (R13 structure — best measured):
//   hout[n] = act( sum_b (sum_e norm*comp[et,b]*h[src]) @ B_b + h[n]@loopw + bias )
// Single-pass gather (all K-slices per edge), meta prefetch 1 ahead,
// 4 basis MFMA phases + self-loop. Wave owns 16 rows.
// Lane l: m=l&15 (row), g=l>>4 (K-subgroup). D: row g*4+ri, col nf*16+m.
// ======================================================================
template<int DIN, int DOUT, int ACT, int IN_F32, int OUT_F32, int MINW>
__global__ __launch_bounds__(256, MINW) void k_fusedb(
        const void* __restrict__ hin, const __bf16* __restrict__ Bt,
        const __bf16* __restrict__ loopt, const float* __restrict__ bias,
        const float* __restrict__ comp, const int* __restrict__ rowptr,
        const int2* __restrict__ pmeta, void* __restrict__ hout) {
    constexpr int KS = DIN/32;
    constexpr int NF = DOUT/16;
    const int tid = threadIdx.x;
    const int w = tid >> 6, l = tid & 63;
    const int m = l & 15, g = l >> 4;
    const int nb = blockIdx.x*64 + w*16;
    const int node = nb + m;

    f32x4 acc[NF];
    #pragma unroll
    for (int nf = 0; nf < NF; ++nf) acc[nf] = (f32x4){0.f,0.f,0.f,0.f};

    float ka[NBAS][KS][8];
    #pragma unroll
    for (int b = 0; b < NBAS; ++b)
        #pragma unroll
        for (int ks = 0; ks < KS; ++ks)
            #pragma unroll
            for (int c = 0; c < 8; ++c) ka[b][ks][c] = 0.f;

    const int jb = rowptr[node], je = rowptr[node+1];
    int2 mt = pmeta[jb];                 // safe: pmeta padded
    for (int j = jb; j < je; ++j) {
        const int2 mtn = pmeta[j+1];     // prefetch next
        const int p = mt.x & 0xFFFFFF;
        const int et = ((unsigned)mt.x) >> 24;
        const float nm = __int_as_float(mt.y);
        const float4 cw = *(const float4*)(comp + et*NBAS);
        const float w0 = nm*cw.x, w1 = nm*cw.y, w2 = nm*cw.z, w3 = nm*cw.w;
        float hv[KS][8];
        if (IN_F32) {
            const float* hp = (const float*)hin + (size_t)p*DIN + g*8;
            #pragma unroll
            for (int ks = 0; ks < KS; ++ks) {
                float4 v0 = *(const float4*)(hp + ks*32);
                float4 v1 = *(const float4*)(hp + ks*32 + 4);
                hv[ks][0]=v0.x; hv[ks][1]=v0.y; hv[ks][2]=v0.z; hv[ks][3]=v0.w;
                hv[ks][4]=v1.x; hv[ks][5]=v1.y; hv[ks][6]=v1.z; hv[ks][7]=v1.w;
            }
        } else {
            const __bf16* hp = (const __bf16*)hin + (size_t)p*DIN + g*8;
            #pragma unroll
            for (int ks = 0; ks < KS; ++ks) {
                bf16x8 v = *(const bf16x8*)(hp + ks*32);
                #pragma unroll
                for (int c = 0; c < 8; ++c) hv[ks][c] = (float)v[c];
            }
        }
        #pragma unroll
        for (int ks = 0; ks < KS; ++ks) {
            #pragma unroll
            for (int c = 0; c < 8; ++c) {
                ka[0][ks][c] += w0*hv[ks][c];
                ka[1][ks][c] += w1*hv[ks][c];
                ka[2][ks][c] += w2*hv[ks][c];
                ka[3][ks][c] += w3*hv[ks][c];
            }
        }
        mt = mtn;
    }

    #pragma unroll
    for (int b = 0; b < NBAS; ++b) {
        #pragma unroll
        for (int ks = 0; ks < KS; ++ks) {
            bf16x8 fa;
            #pragma unroll
            for (int c = 0; c < 8; ++c) fa[c] = (__bf16)ka[b][ks][c];
            #pragma unroll
            for (int nf = 0; nf < NF; ++nf) {
                bf16x8 fb = *(const bf16x8*)(Bt + ((size_t)b*DOUT + nf*16 + m)*DIN
                                             + ks*32 + g*8);
                acc[nf] = __builtin_amdgcn_mfma_f32_16x16x32_bf16(fa, fb, acc[nf], 0, 0, 0);
            }
        }
    }

    #pragma unroll
    for (int ks = 0; ks < KS; ++ks) {
        bf16x8 fa;
        if (IN_F32) {
            const float* hp = (const float*)hin + (size_t)node*DIN + ks*32 + g*8;
            float4 v0 = *(const float4*)hp;
            float4 v1 = *(const float4*)(hp + 4);
            fa[0]=(__bf16)v0.x; fa[1]=(__bf16)v0.y; fa[2]=(__bf16)v0.z; fa[3]=(__bf16)v0.w;
            fa[4]=(__bf16)v1.x; fa[5]=(__bf16)v1.y; fa[6]=(__bf16)v1.z; fa[7]=(__bf16)v1.w;
        } else {
            fa = *(const bf16x8*)((const __bf16*)hin + (size_t)node*DIN + ks*32 + g*8);
        }
        #pragma unroll
        for (int nf = 0; nf < NF; ++nf) {
            bf16x8 fb = *(const bf16x8*)(loopt + (size_t)(nf*16 + m)*DIN + ks*32 + g*8);
            acc[nf] = __builtin_amdgcn_mfma_f32_16x16x32_bf16(fa, fb, acc[nf], 0, 0, 0);
        }
    }

    #pragma unroll
    for (int nf = 0; nf < NF; ++nf) {
        const int col = nf*16 + m;
        const float bv = bias[col];
        #pragma unroll
        for (int ri = 0; ri < 4; ++ri) {
            const int orow = nb + g*4 + ri;
            float v = acc[nf][ri] + bv;
            if (ACT == 0) v = (v >= 0.f) ? v : NEG_SLOPE*v;
            else          v = 1.f/(1.f + __expf(-v));
            if (OUT_F32) ((float*)hout)[(size_t)orow*DOUT + col] = v;
            else         ((__bf16*)hout)[(size_t)orow*DOUT + col] = (__bf16)v;
        }
    }
}

// ======================================================================
// conv-transpose decoder + sigmoid, f32 logits, branchless phase taps.
// ======================================================================
__global__ __launch_bounds__(256) void k_convt_f32(const float* __restrict__ logits,
        const float* __restrict__ w, const float* __restrict__ cb, float* __restrict__ out) {
    __shared__ float s_w[49*32];   // [tap][c]
    const int tid = threadIdx.x;
    for (int idx = tid; idx < 49*32; idx += 256) {
        int tap = idx/32, c = idx%32;
        s_w[tap*32 + c] = w[c*49 + tap];
    }
    __syncthreads();
    int gidx = blockIdx.x*256 + tid;
    if (gidx >= B_GR*IWID*IWID) return;
    int b = gidx/(IWID*IWID);
    int rem = gidx%(IWID*IWID);
    int oy = rem/IWID, ox = rem%IWID;

    const int py = (oy+2)%3, qy = (oy+2)/3;
    const int px = (ox+2)%3, qx = (ox+2)/3;

    float acc = cb[0];
    #pragma unroll
    for (int sy = 0; sy < 3; ++sy) {
        const int ky = py + 3*sy;
        const int iy = qy - sy;
        if (ky > 6 || iy < 0 || iy >= GWID) continue;
        #pragma unroll
        for (int sx = 0; sx < 3; ++sx) {
            const int kx = px + 3*sx;
            const int ix = qx - sx;
            if (kx > 6 || ix < 0 || ix >= GWID) continue;
            const float4* xp = (const float4*)&logits[(((size_t)b*GWID + iy)*GWID + ix)*32];
            const float4* wp = (const float4*)&s_w[(ky*7 + kx)*32];
            #pragma unroll
            for (int c4 = 0; c4 < 8; ++c4) {
                float4 xv = xp[c4], wv = wp[c4];
                acc += xv.x*wv.x + xv.y*wv.y + xv.z*wv.z + xv.w*wv.w;
            }
        }
    }
    out[gidx] = 1.f/(1.f + __expf(-acc));
}

// ======================================================================
// host
// ======================================================================
extern "C" void kernel_launch(void* const* d_in, const int* in_sizes, int n_in,
                              void* d_out, int out_size, void* d_ws, size_t ws_size,
                              hipStream_t stream) {
    const float* features = (const float*)d_in[0];
    const int*   src      = (const int*)  d_in[1];
    const int*   dst      = (const int*)  d_in[2];
    const int*   etypes   = (const int*)  d_in[3];
    const float* norm     = (const float*)d_in[4];
    const float* bases0 = (const float*)d_in[5];
    const float* comp0  = (const float*)d_in[6];
    const float* loop0  = (const float*)d_in[7];
    const float* bias0  = (const float*)d_in[8];
    const float* bases1 = (const float*)d_in[9];
    const float* comp1  = (const float*)d_in[10];
    const float* loop1  = (const float*)d_in[11];
    const float* bias1  = (const float*)d_in[12];
    const float* bases2 = (const float*)d_in[13];
    const float* comp2  = (const float*)d_in[14];
    const float* loop2  = (const float*)d_in[15];
    const float* bias2  = (const float*)d_in[16];
    const float* conv_w = (const float*)d_in[17];
    const float* conv_b = (const float*)d_in[18];
    float* out = (float*)d_out;

    const int ebl = (E_EDGES + 255)/256;
    float* ws = (float*)d_ws;
    auto pad4 = [](size_t v){ return (v + 3) & ~(size_t)3; };

    // ---- workspace carve (float units), total ~60 MB ----
    size_t off = 0;
    __bf16* Bt0   = (__bf16*)(ws + off); off += (size_t)NBAS*32*64/2;
    __bf16* Bt1   = (__bf16*)(ws + off); off += (size_t)NBAS*64*64/2;
    __bf16* Bt2   = (__bf16*)(ws + off); off += (size_t)NBAS*64*32/2;
    __bf16* lt0   = (__bf16*)(ws + off); off += (size_t)64*32/2;
    __bf16* lt1   = (__bf16*)(ws + off); off += (size_t)64*64/2;
    __bf16* lt2   = (__bf16*)(ws + off); off += (size_t)32*64/2;
    __bf16* fbf   = (__bf16*)(ws + off); off += (size_t)N_NODES*C_IN/2;   // bf16 features
    __bf16* h1    = (__bf16*)(ws + off); off += (size_t)N_NODES*64/2;
    __bf16* h2    = (__bf16*)(ws + off); off += (size_t)N_NODES*64/2;
    float*  lg    = (float*)(ws + off);  off += (size_t)N_NODES*32;   // f32 logits
    int* rowptr   = (int*)(ws + off); off += pad4((size_t)N_NODES + 4);
    int* deg      = (int*)(ws + off); off += (size_t)N_NODES;   // becomes cursor
    int* bsum     = (int*)(ws + off); off += 512;
    int2* pmeta   = (int2*)(ws + off); off += (size_t)(E_EDGES + 8)*2;  // +8 pad

    // ---- weight prep (transposed bf16 basis + loop tables) + feature cvt ----
    k_bases_t<<<(NBAS*32*64 + 255)/256, 256, 0, stream>>>(bases0, Bt0, 32, 64);
    k_bases_t<<<(NBAS*64*64 + 255)/256, 256, 0, stream>>>(bases1, Bt1, 64, 64);
    k_bases_t<<<(NBAS*64*32 + 255)/256, 256, 0, stream>>>(bases2, Bt2, 64, 32);
    k_loop_t<<<(32*64 + 255)/256, 256, 0, stream>>>(loop0, lt0, 32, 64);
    k_loop_t<<<(64*64 + 255)/256, 256, 0, stream>>>(loop1, lt1, 64, 64);
    k_loop_t<<<(64*32 + 255)/256, 256, 0, stream>>>(loop2, lt2, 64, 32);
    k_feat2bf<<<(N_NODES*C_IN/8 + 255)/256, 256, 0, stream>>>(features, fbf);

    // ---- dst-CSR + single packed scatter (reused by all 3 layers) ----
    hipMemsetAsync(deg, 0, (size_t)N_NODES*sizeof(int), stream);
    k_deg  <<<ebl, 256, 0, stream>>>(dst, deg);
    k_scan1<<<SCAN_BLOCKS, 256, 0, stream>>>(deg, rowptr, bsum);
    k_scan2<<<1, 512, 0, stream>>>(bsum, rowptr);
    k_scan3<<<SCAN_BLOCKS, 256, 0, stream>>>(rowptr, bsum, deg);
    k_scatter_pack<<<ebl, 256, 0, stream>>>(src, dst, etypes, norm, deg, pmeta);

    const int NROWT = N_NODES/64;   // 1800

    // ---- 3 fused basis layers (R13 structure; L0 reads bf16 features) ----
    k_fusedb<32,64,0,0,0,4><<<NROWT, 256, 0, stream>>>(fbf, Bt0, lt0, bias0, comp0,
                                                       rowptr, pmeta, h1);
    k_fusedb<64,64,0,0,0,3><<<NROWT, 256, 0, stream>>>(h1, Bt1, lt1, bias1, comp1,
                                                       rowptr, pmeta, h2);
    k_fusedb<64,32,1,0,1,3><<<NROWT, 256, 0, stream>>>(h2, Bt2, lt2, bias2, comp2,
                                                       rowptr, pmeta, lg);

    // ---- decoder (f32 logits) ----
    k_convt_f32<<<(B_GR*IWID*IWID + 255)/256, 256, 0, stream>>>(lg, conv_w, conv_b, out);
}